// Round 6
// baseline (483.073 us; speedup 1.0000x reference)
//
#include <hip/hip_runtime.h>

// B=4, S=4096, L=256 decoder block, algebraically collapsed (exact):
//  scores[b,s,t] = x_s^T M x_t with x_t = cp_t*(tp_t, ti_t, 1); M = 3x3 of
//  256-dim dots (scale folded in).  v rank-1 + softmax normalization =>
//  per-row scalar A_s = sum(w_t * ti_t)/sum(w_t).
//  MLP head: h = A*c1 + cp*c2 + c3 -> leaky -> 128x32 -> leaky -> 32x2.
// float4-interleaved X stream (1 dwordx4/element instead of 3 dwords),
// __expf (validated in R1), float4 LDS reads in MLP, unroll-2 t-loop.

#define SEQ 4096
#define NB 4

// ws float layout:
//   [0..8]        M' = scale * M (row-major)
//   [16..143]     c1
//   [160..287]    c2
//   [288..415]    c3
//   [1024..66559] X  (NB*SEQ float4, 16B aligned)
//   [66560..]     A  (NB*SEQ floats)

__global__ __launch_bounds__(256) void pre_kernel(
    const float* __restrict__ tp, const float* __restrict__ cp,
    const float* __restrict__ ti,
    const float* __restrict__ wq_w, const float* __restrict__ wq_b,
    const float* __restrict__ wk_w, const float* __restrict__ wk_b,
    const float* __restrict__ wv_w, const float* __restrict__ wv_b,
    const float* __restrict__ a2_w, const float* __restrict__ a2_b,
    const float* __restrict__ a3_w, const float* __restrict__ a3_b,
    float* __restrict__ ws)
{
    const int tid = threadIdx.x;
    const int p = blockIdx.x * 256 + tid;       // 0..16383
    const float cpv = cp[p], tpv = tp[p], tiv = ti[p];
    float4* X = (float4*)(ws + 1024);
    X[p] = make_float4(cpv * tpv, cpv * tiv, cpv, tiv);

    if (blockIdx.x != 0) return;
    if (tid < 128) {
        float c1 = 0.f, c3 = 0.f;
        for (int l = 0; l < 256; ++l) {
            const float a2 = a2_w[l * 128 + tid];
            c1 = fmaf(wv_w[l], a2, c1);
            c3 = fmaf(wv_b[l], a2, c3);
        }
        ws[16 + tid]  = c1;
        ws[160 + tid] = a3_w[tid];
        ws[288 + tid] = c3 + a2_b[tid] + a3_b[tid];
    } else if (tid < 137) {
        const int idx = tid - 128;
        const int i = idx / 3, j = idx % 3;
        const float* qv = (i == 0) ? wq_w : (i == 1) ? (wq_w + 256) : wq_b;
        const float* kv = (j == 0) ? wk_w : (j == 1) ? (wk_w + 256) : wk_b;
        float m = 0.f;
        for (int l = 0; l < 256; ++l) m = fmaf(qv[l], kv[l], m);
        ws[i * 3 + j] = m * 0.0625f;   // fold scale = 1/sqrt(256)
    }
}

// One wave handles rows s=r and s=SEQ-1-r of one batch: uniform 4097
// elements per wave -> perfect load balance. 8192 waves = 2048 blocks.
__global__ __launch_bounds__(256) void attn_kernel(
    const float* __restrict__ ws,
    float* __restrict__ A)
{
    const int wave = (blockIdx.x * blockDim.x + threadIdx.x) >> 6; // 0..8191
    const int lane = threadIdx.x & 63;
    const int b = wave >> 11;
    const int r = wave & 2047;

    const float M00 = ws[0], M01 = ws[1], M02 = ws[2];
    const float M10 = ws[3], M11 = ws[4], M12 = ws[5];
    const float M20 = ws[6], M21 = ws[7], M22 = ws[8];

    const float4* __restrict__ Xb = (const float4*)(ws + 1024) + b * SEQ;

    #pragma unroll
    for (int pick = 0; pick < 2; ++pick) {
        const int s = pick ? (SEQ - 1 - r) : r;
        const float4 xs = Xb[s];               // (cp*tp, cp*ti, cp, ti)
        const float d0 = M00 * xs.x + M10 * xs.y + M20 * xs.z;
        const float d1 = M01 * xs.x + M11 * xs.y + M21 * xs.z;
        const float d2 = M02 * xs.x + M12 * xs.y + M22 * xs.z;

        float lsum = 0.f, asum = 0.f;
        int t = lane;
        // unrolled by 2: two dwordx4 loads in flight per iteration
        for (; t + 64 <= s; t += 128) {
            const float4 xa = Xb[t];
            const float4 xb = Xb[t + 64];
            const float sa = fmaf(d0, xa.x, fmaf(d1, xa.y, d2 * xa.z));
            const float sb = fmaf(d0, xb.x, fmaf(d1, xb.y, d2 * xb.z));
            const float wa = __expf(sa);
            const float wb = __expf(sb);
            lsum += wa + wb;
            asum = fmaf(wa, xa.w, fmaf(wb, xb.w, asum));
        }
        if (t <= s) {
            const float4 xa = Xb[t];
            const float sa = fmaf(d0, xa.x, fmaf(d1, xa.y, d2 * xa.z));
            const float wa = __expf(sa);
            lsum += wa;
            asum = fmaf(wa, xa.w, asum);
        }
        #pragma unroll
        for (int off = 32; off; off >>= 1) {
            lsum += __shfl_down(lsum, off, 64);
            asum += __shfl_down(asum, off, 64);
        }
        if (lane == 0) A[b * SEQ + s] = asum / lsum;
    }
}

// One thread per position: h(128) -> leaky -> @a4(128x32) -> leaky -> @a5(32x2)
__global__ __launch_bounds__(64) void mlp_kernel(
    const float* __restrict__ A,
    const float* __restrict__ cp,
    const float* __restrict__ ws,
    const float* __restrict__ a4_w, // 128*32
    const float* __restrict__ a4_b, // 32
    const float* __restrict__ a5_w, // 32*2
    const float* __restrict__ a5_b, // 2
    float* __restrict__ out)        // B*S*2
{
    __shared__ float sc1[128], sc2[128], sc3[128];
    __shared__ float4 sa4[1024];                 // 128x32 as float4
    const int tid = threadIdx.x;
    for (int i = tid; i < 128; i += 64) {
        sc1[i] = ws[16 + i];
        sc2[i] = ws[160 + i];
        sc3[i] = ws[288 + i];
    }
    const float4* a4v = (const float4*)a4_w;
    for (int i = tid; i < 1024; i += 64) sa4[i] = a4v[i];
    __syncthreads();

    const int p = blockIdx.x * 64 + tid;         // 0..16383
    const float Av = A[p], cpv = cp[p];

    float4 acc[8];
    #pragma unroll
    for (int k = 0; k < 8; ++k) acc[k] = ((const float4*)a4_b)[k];

    for (int j = 0; j < 128; ++j) {
        float h = fmaf(Av, sc1[j], fmaf(cpv, sc2[j], sc3[j]));
        h = (h >= 0.f) ? h : 0.2f * h;
        #pragma unroll
        for (int k = 0; k < 8; ++k) {
            const float4 w4 = sa4[j * 8 + k];
            acc[k].x = fmaf(h, w4.x, acc[k].x);
            acc[k].y = fmaf(h, w4.y, acc[k].y);
            acc[k].z = fmaf(h, w4.z, acc[k].z);
            acc[k].w = fmaf(h, w4.w, acc[k].w);
        }
    }

    float o0 = a5_b[0], o1 = a5_b[1];
    #pragma unroll
    for (int k = 0; k < 8; ++k) {
        const float* av = (const float*)&acc[k];
        #pragma unroll
        for (int c = 0; c < 4; ++c) {
            const int j2 = k * 4 + c;
            const float h2 = (av[c] >= 0.f) ? av[c] : 0.2f * av[c];
            o0 = fmaf(h2, a5_w[j2 * 2 + 0], o0);
            o1 = fmaf(h2, a5_w[j2 * 2 + 1], o1);
        }
    }
    ((float2*)out)[p] = make_float2(o0, o1);
}

extern "C" void kernel_launch(void* const* d_in, const int* in_sizes, int n_in,
                              void* d_out, int out_size, void* d_ws, size_t ws_size,
                              hipStream_t stream) {
    const float* tp   = (const float*)d_in[0];
    const float* cp   = (const float*)d_in[1];
    const float* ti   = (const float*)d_in[2];
    const float* wq_w = (const float*)d_in[6];
    const float* wq_b = (const float*)d_in[7];
    const float* wk_w = (const float*)d_in[8];
    const float* wk_b = (const float*)d_in[9];
    const float* wv_w = (const float*)d_in[10];
    const float* wv_b = (const float*)d_in[11];
    const float* a2_w = (const float*)d_in[12];
    const float* a2_b = (const float*)d_in[13];
    const float* a3_w = (const float*)d_in[14];
    const float* a3_b = (const float*)d_in[15];
    const float* a4_w = (const float*)d_in[16];
    const float* a4_b = (const float*)d_in[17];
    const float* a5_w = (const float*)d_in[18];
    const float* a5_b = (const float*)d_in[19];

    float* ws  = (float*)d_ws;
    float* A   = ws + 66560;
    float* out = (float*)d_out;

    hipLaunchKernelGGL(pre_kernel, dim3(64), dim3(256), 0, stream,
                       tp, cp, ti, wq_w, wq_b, wk_w, wk_b, wv_w, wv_b,
                       a2_w, a2_b, a3_w, a3_b, ws);
    hipLaunchKernelGGL(attn_kernel, dim3(2048), dim3(256), 0, stream,
                       ws, A);
    hipLaunchKernelGGL(mlp_kernel, dim3(256), dim3(64), 0, stream,
                       A, cp, ws, a4_w, a4_b, a5_w, a5_b, out);
}